// Round 3
// baseline (425.479 us; speedup 1.0000x reference)
//
#include <hip/hip_runtime.h>
#include <hip/hip_bf16.h>

// QuantizedLinear: out[64,8192] = x[64,8192] @ (alpha * ternary(W))^T + bias
// R3: contiguity-first. R1/R2 both hit a 162us wall independent of HBM traffic
// (same dur at 155MB vs 17MB fetch) -> 32KB-row-strided 64B-segment gathers
// serialize in L2 slices. Fix: every global load instruction is a single
// contiguous 1KB wave burst.
//   - W: per instr, 64 lanes x float4 along k of ONE row (BK=256); ternarize
//     in-register -> bf16 LDS tile [64][264] (528B stride: 16B-aligned,
//     uniform banks).
//   - x: prep kernel pre-permutes x into MFMA A-fragment order in d_ws, so
//     A-frags load straight from global as contiguous 1KB wave reads
//     (L2-resident), no LDS, no barrier coupling.

typedef __attribute__((ext_vector_type(8))) short short8;   // 8 bf16
typedef __attribute__((ext_vector_type(4))) float floatx4;  // MFMA acc

#define B_DIM 64
#define K_DIM 8192
#define O_DIM 8192
#define KSPLIT 8
#define KCHUNK 1024               // k per block
#define BK 256                    // fp32 k per LDS step
#define KSTEPS (KCHUNK / BK)      // 4
#define LDSW 264                  // shorts per LDS row: 528B, 16B-aligned, 132dw==4 mod 32

__device__ __forceinline__ unsigned short tq(float v, float thr) {
  // +1 -> 0x3F80, -1 -> 0xBF80, 0 -> 0 (bf16 bit patterns)
  return v > thr ? (unsigned short)0x3F80
                 : (v < -thr ? (unsigned short)0xBF80 : (unsigned short)0);
}

// ---- prep: x -> bf16 in MFMA-A-fragment order; out = bias broadcast ----
// A-frag (16x16x32): lane ln holds A[m = ln&15][k = (ln>>4)*8 + j], j=0..7.
// Layout: xfrag[ ((kb*4 + mt)*64 + lane)*8 + j ]  (shorts), kb = k>>5, mt = m>>4.
__global__ __launch_bounds__(256) void prep_kernel(
    const float* __restrict__ x, const float* __restrict__ bias,
    unsigned short* __restrict__ xfrag, float* __restrict__ out) {
  const int gid = blockIdx.x * 256 + threadIdx.x;  // 0..65535 (one k-octet each)
  const int b  = gid >> 10;        // 0..63
  const int ko = gid & 1023;       // k-octet within row
  const float* src = x + (size_t)b * K_DIM + (size_t)ko * 8;
  float4 v0 = *(const float4*)src;
  float4 v1 = *(const float4*)(src + 4);
  short8 o;
  o[0] = (short)(unsigned short)__bfloat16_as_ushort(__float2bfloat16(v0.x));
  o[1] = (short)(unsigned short)__bfloat16_as_ushort(__float2bfloat16(v0.y));
  o[2] = (short)(unsigned short)__bfloat16_as_ushort(__float2bfloat16(v0.z));
  o[3] = (short)(unsigned short)__bfloat16_as_ushort(__float2bfloat16(v0.w));
  o[4] = (short)(unsigned short)__bfloat16_as_ushort(__float2bfloat16(v1.x));
  o[5] = (short)(unsigned short)__bfloat16_as_ushort(__float2bfloat16(v1.y));
  o[6] = (short)(unsigned short)__bfloat16_as_ushort(__float2bfloat16(v1.z));
  o[7] = (short)(unsigned short)__bfloat16_as_ushort(__float2bfloat16(v1.w));
  const int kb  = ko >> 2;         // 32-wide k-block
  const int lhi = ko & 3;          // k-quad within block
  const int mt  = b >> 4;
  const int llo = b & 15;
  const size_t d = ((size_t)(kb * 4 + mt) * 64 + (size_t)(lhi * 16 + llo)) * 8;
  *(short8*)(xfrag + d) = o;

  // out init: 8 consecutive floats per thread (8 | O_DIM so same bias window)
  const int o0 = (gid * 8) & (O_DIM - 1);
  float4 b0 = *(const float4*)(bias + o0);
  float4 b1 = *(const float4*)(bias + o0 + 4);
  *(float4*)(out + (size_t)gid * 8)     = b0;
  *(float4*)(out + (size_t)gid * 8 + 4) = b1;
}

// ---- main GEMM: 1024 blocks (128 n-tiles x 8 k-slices), 256 thr ----
__global__ __launch_bounds__(256, 2) void gemm_kernel(
    const float* __restrict__ w, const unsigned short* __restrict__ xfrag,
    const float* __restrict__ alpha, float* __restrict__ out) {
  __shared__ __align__(16) short Ws[64 * LDSW];   // 33.8 KB
  __shared__ float thr_lds[64];

  const int tid = threadIdx.x;
  const int nt  = blockIdx.x & 127;   // n-tile
  const int ks  = blockIdx.x >> 7;    // k-slice 0..7
  const int wv  = tid >> 6;           // wave -> 16-row n sub-tile
  const int ln  = tid & 63;
  const int llo = ln & 15;
  const int lhi = ln >> 4;
  const int n0  = nt * 64;
  const size_t k0 = (size_t)ks * KCHUNK;

  if (tid < 64) thr_lds[tid] = 0.5f * (alpha[n0 + tid] + 1e-8f);

  // W staging: wave wv stages rows wv*16..+15; instr t = one row, lane ln = float4 at 4*ln
  const float* wbase = w + (size_t)(n0 + wv * 16) * K_DIM + k0 + (size_t)(4 * ln);

  floatx4 acc[4];
#pragma unroll
  for (int i = 0; i < 4; ++i) acc[i] = (floatx4){0.f, 0.f, 0.f, 0.f};

  float4 wbuf[16];

  auto load_w = [&](int s) {
#pragma unroll
    for (int t = 0; t < 16; ++t)
      wbuf[t] = *(const float4*)(wbase + (size_t)t * K_DIM + (size_t)s * BK);
  };

  auto write_w = [&]() {
#pragma unroll
    for (int t = 0; t < 16; ++t) {
      const int row = wv * 16 + t;
      const float thr = thr_lds[row];           // wave-uniform
      ushort4 p;
      p.x = tq(wbuf[t].x, thr);
      p.y = tq(wbuf[t].y, thr);
      p.z = tq(wbuf[t].z, thr);
      p.w = tq(wbuf[t].w, thr);
      *(ushort4*)&Ws[row * LDSW + 4 * ln] = p;  // byte = row*528 + 8*ln
    }
  };

  const short8* ap = (const short8*)(const void*)xfrag;

  auto compute = [&](int s) {
    const int kb0 = ks * 32 + s * 8;
#pragma unroll
    for (int kk = 0; kk < 8; ++kk) {
      short8 bf = *(const short8*)&Ws[(wv * 16 + llo) * LDSW + kk * 32 + lhi * 8];
#pragma unroll
      for (int mt = 0; mt < 4; ++mt) {
        short8 af = ap[(size_t)((kb0 + kk) * 4 + mt) * 64 + ln];  // contiguous 1KB wave read
        acc[mt] = __builtin_amdgcn_mfma_f32_16x16x32_bf16(af, bf, acc[mt], 0, 0, 0);
      }
    }
  };

  load_w(0);
  __syncthreads();                     // thr_lds ready
  for (int s = 0; s < KSTEPS; ++s) {
    write_w();                         // waits on wbuf vmcnt
    __syncthreads();                   // Ws visible
    if (s + 1 < KSTEPS) load_w(s + 1); // next HBM burst in flight across compute
    compute(s);
    if (s + 1 < KSTEPS) __syncthreads();  // all waves done reading Ws
  }

  // epilogue (validated in R2): C/D col = llo (n), row = lhi*4 + r within m-tile
  const int nrow = n0 + wv * 16 + llo;
  const float av = alpha[nrow];
#pragma unroll
  for (int mt = 0; mt < 4; ++mt) {
    const int m = mt * 16 + lhi * 4;
#pragma unroll
    for (int r = 0; r < 4; ++r) {
      atomicAdd(&out[(size_t)(m + r) * O_DIM + nrow], acc[mt][r] * av);
    }
  }
}

extern "C" void kernel_launch(void* const* d_in, const int* in_sizes, int n_in,
                              void* d_out, int out_size, void* d_ws, size_t ws_size,
                              hipStream_t stream) {
  const float* x     = (const float*)d_in[0];  // [64, 8192]
  const float* w     = (const float*)d_in[1];  // [8192, 8192]
  const float* alpha = (const float*)d_in[2];  // [8192, 1]
  const float* bias  = (const float*)d_in[3];  // [8192]
  float* out = (float*)d_out;                  // [64, 8192]
  unsigned short* xfrag = (unsigned short*)d_ws;  // 1 MB, A-fragment order

  prep_kernel<<<(B_DIM * K_DIM / 8) / 256, 256, 0, stream>>>(x, bias, xfrag, out);
  gemm_kernel<<<(O_DIM / 64) * KSPLIT, 256, 0, stream>>>(w, xfrag, alpha, out);
}

// Round 4
// 423.736 us; speedup vs baseline: 1.0041x; 1.0041x over previous
//
#include <hip/hip_runtime.h>
#include <hip/hip_bf16.h>

// QuantizedLinear: out[64,8192] = x[64,8192] @ (alpha * ternary(W))^T + bias
// R4: kill the atomics. R1-R3 all pinned at ~162us regardless of compute
// structure or HBM traffic -> the shared 4.19M device-scope fp32 atomicAdd
// epilogue is the wall (cross-XCD coherence serialization). Replace with
// split-K partial buffers (plain stores, no contention) + a small reduce
// kernel that folds bias. Compute phase unchanged from R3 (contiguous 1KB
// wave bursts for W, pre-permuted A-fragments for x).

typedef __attribute__((ext_vector_type(8))) short short8;   // 8 bf16
typedef __attribute__((ext_vector_type(4))) float floatx4;  // MFMA acc

#define B_DIM 64
#define K_DIM 8192
#define O_DIM 8192
#define KSPLIT 8
#define KCHUNK 1024               // k per block
#define BK 256                    // fp32 k per LDS step
#define KSTEPS (KCHUNK / BK)      // 4
#define LDSW 264                  // shorts per LDS row: 528B, 16B-aligned

__device__ __forceinline__ unsigned short tq(float v, float thr) {
  // +1 -> 0x3F80, -1 -> 0xBF80, 0 -> 0 (bf16 bit patterns)
  return v > thr ? (unsigned short)0x3F80
                 : (v < -thr ? (unsigned short)0xBF80 : (unsigned short)0);
}

// ---- prep: x -> bf16 in MFMA-A-fragment order ----
// A-frag (16x16x32): lane ln holds A[m = ln&15][k = (ln>>4)*8 + j], j=0..7.
// Layout: xfrag[ ((kb*4 + mt)*64 + lane)*8 + j ]  (shorts), kb = k>>5, mt = m>>4.
__global__ __launch_bounds__(256) void prep_kernel(
    const float* __restrict__ x, unsigned short* __restrict__ xfrag) {
  const int gid = blockIdx.x * 256 + threadIdx.x;  // 0..65535 (one k-octet each)
  const int b  = gid >> 10;        // 0..63
  const int ko = gid & 1023;       // k-octet within row
  const float* src = x + (size_t)b * K_DIM + (size_t)ko * 8;
  float4 v0 = *(const float4*)src;
  float4 v1 = *(const float4*)(src + 4);
  short8 o;
  o[0] = (short)__bfloat16_as_ushort(__float2bfloat16(v0.x));
  o[1] = (short)__bfloat16_as_ushort(__float2bfloat16(v0.y));
  o[2] = (short)__bfloat16_as_ushort(__float2bfloat16(v0.z));
  o[3] = (short)__bfloat16_as_ushort(__float2bfloat16(v0.w));
  o[4] = (short)__bfloat16_as_ushort(__float2bfloat16(v1.x));
  o[5] = (short)__bfloat16_as_ushort(__float2bfloat16(v1.y));
  o[6] = (short)__bfloat16_as_ushort(__float2bfloat16(v1.z));
  o[7] = (short)__bfloat16_as_ushort(__float2bfloat16(v1.w));
  const int kb  = ko >> 2;         // 32-wide k-block
  const int lhi = ko & 3;          // k-quad within block
  const int mt  = b >> 4;
  const int llo = b & 15;
  const size_t d = ((size_t)(kb * 4 + mt) * 64 + (size_t)(lhi * 16 + llo)) * 8;
  *(short8*)(xfrag + d) = o;
}

// ---- main GEMM: 1024 blocks (128 n-tiles x 8 k-slices), 256 thr ----
__global__ __launch_bounds__(256, 2) void gemm_kernel(
    const float* __restrict__ w, const unsigned short* __restrict__ xfrag,
    const float* __restrict__ alpha, float* __restrict__ part) {
  __shared__ __align__(16) short Ws[64 * LDSW];   // 33.8 KB
  __shared__ float thr_lds[64];

  const int tid = threadIdx.x;
  const int nt  = blockIdx.x & 127;   // n-tile (fast dim: co-resident blocks share ks -> xfrag L2 reuse)
  const int ks  = blockIdx.x >> 7;    // k-slice 0..7
  const int wv  = tid >> 6;           // wave -> 16-row n sub-tile
  const int ln  = tid & 63;
  const int llo = ln & 15;
  const int lhi = ln >> 4;
  const int n0  = nt * 64;
  const size_t k0 = (size_t)ks * KCHUNK;

  if (tid < 64) thr_lds[tid] = 0.5f * (alpha[n0 + tid] + 1e-8f);

  // W staging: wave wv stages rows wv*16..+15; instr t = one row, lane ln = float4 at 4*ln
  const float* wbase = w + (size_t)(n0 + wv * 16) * K_DIM + k0 + (size_t)(4 * ln);

  floatx4 acc[4];
#pragma unroll
  for (int i = 0; i < 4; ++i) acc[i] = (floatx4){0.f, 0.f, 0.f, 0.f};

  float4 wbuf[16];

  auto load_w = [&](int s) {
#pragma unroll
    for (int t = 0; t < 16; ++t)
      wbuf[t] = *(const float4*)(wbase + (size_t)t * K_DIM + (size_t)s * BK);
  };

  auto write_w = [&]() {
#pragma unroll
    for (int t = 0; t < 16; ++t) {
      const int row = wv * 16 + t;
      const float thr = thr_lds[row];           // wave-uniform
      ushort4 p;
      p.x = tq(wbuf[t].x, thr);
      p.y = tq(wbuf[t].y, thr);
      p.z = tq(wbuf[t].z, thr);
      p.w = tq(wbuf[t].w, thr);
      *(ushort4*)&Ws[row * LDSW + 4 * ln] = p;  // byte = row*528 + 8*ln
    }
  };

  const short8* ap = (const short8*)(const void*)xfrag;

  auto compute = [&](int s) {
    const int kb0 = ks * 32 + s * 8;
#pragma unroll
    for (int kk = 0; kk < 8; ++kk) {
      short8 bf = *(const short8*)&Ws[(wv * 16 + llo) * LDSW + kk * 32 + lhi * 8];
#pragma unroll
      for (int mt = 0; mt < 4; ++mt) {
        short8 af = ap[(size_t)((kb0 + kk) * 4 + mt) * 64 + ln];  // contiguous 1KB wave read
        acc[mt] = __builtin_amdgcn_mfma_f32_16x16x32_bf16(af, bf, acc[mt], 0, 0, 0);
      }
    }
  };

  load_w(0);
  __syncthreads();                     // thr_lds ready
  for (int s = 0; s < KSTEPS; ++s) {
    write_w();                         // waits on wbuf vmcnt
    __syncthreads();                   // Ws visible
    if (s + 1 < KSTEPS) load_w(s + 1); // next HBM burst in flight across compute
    compute(s);
    if (s + 1 < KSTEPS) __syncthreads();  // all waves done reading Ws
  }

  // epilogue: plain stores to per-block slab part[ks][nt][m*64 + n_local].
  // C/D layout (validated R1-R3): col = llo (n), row = lhi*4 + r within m-tile.
  const float av = alpha[n0 + wv * 16 + llo];
  float* pb = part + (size_t)blockIdx.x * 4096;   // blockIdx.x == ks*128 + nt
  const int ncol = wv * 16 + llo;
#pragma unroll
  for (int mt = 0; mt < 4; ++mt) {
    const int m = mt * 16 + lhi * 4;
#pragma unroll
    for (int r = 0; r < 4; ++r) {
      pb[(m + r) * 64 + ncol] = acc[mt][r] * av;
    }
  }
}

// ---- reduce: out[m][o] = bias[o] + sum_ks part[ks][o>>6][m*64 + (o&63)] ----
__global__ __launch_bounds__(256) void reduce_kernel(
    const float* __restrict__ part, const float* __restrict__ bias,
    float* __restrict__ out) {
  const int gid = blockIdx.x * 256 + threadIdx.x;  // 0..131071 (4 outputs each)
  const int m  = gid >> 11;         // 0..63
  const int oq = gid & 2047;
  const int o0 = oq * 4;
  const int nt = o0 >> 6;
  const int lo = o0 & 63;
  const float* p = part + (size_t)nt * 4096 + m * 64 + lo;
  float4 s = *(const float4*)(bias + o0);
#pragma unroll
  for (int ks = 0; ks < KSPLIT; ++ks) {
    float4 v = *(const float4*)(p + (size_t)ks * 128 * 4096);
    s.x += v.x; s.y += v.y; s.z += v.z; s.w += v.w;
  }
  *(float4*)(out + (size_t)m * O_DIM + o0) = s;
}

extern "C" void kernel_launch(void* const* d_in, const int* in_sizes, int n_in,
                              void* d_out, int out_size, void* d_ws, size_t ws_size,
                              hipStream_t stream) {
  const float* x     = (const float*)d_in[0];  // [64, 8192]
  const float* w     = (const float*)d_in[1];  // [8192, 8192]
  const float* alpha = (const float*)d_in[2];  // [8192, 1]
  const float* bias  = (const float*)d_in[3];  // [8192]
  float* out = (float*)d_out;                  // [64, 8192]
  unsigned short* xfrag = (unsigned short*)d_ws;             // 1 MB, A-frag order
  float* part = (float*)((char*)d_ws + (1 << 20));           // 16.8 MB partials

  prep_kernel<<<(B_DIM * K_DIM / 8) / 256, 256, 0, stream>>>(x, xfrag);
  gemm_kernel<<<(O_DIM / 64) * KSPLIT, 256, 0, stream>>>(w, xfrag, alpha, part);
  reduce_kernel<<<(B_DIM * O_DIM / 4) / 256, 256, 0, stream>>>(part, bias, out);
}